// Round 3
// baseline (391.628 us; speedup 1.0000x reference)
//
#include <hip/hip_runtime.h>
#include <stdint.h>

#define N_ANCH   100800
#define NUM_CLS  80
#define IMG_HW   1280
#define MAX_DETS 300
#define OUTSZ    224
#define CAND_CAP 4096      // compacted (above-threshold) candidates in k_detect
#define LIST_CAP 16384     // raw masked candidates appended by k_score (~11k typical)

// d_out layout (float elements):
// [0,1200) boxes | [1200,1500) scores | [1500,1800) classes |
// [1800, 1800+45308928) crops | [45310728, 45311028) keep
#define OFF_BOXES   0
#define OFF_SCORES  1200
#define OFF_CLASSES 1500
#define OFF_CROPS   1800
#define CROPS_ELEMS (301 * 3 * 224 * 224)
#define OFF_KEEP    (OFF_CROPS + CROPS_ELEMS)

// scratch byte offsets inside crop region (base = (char*)d_out + OFF_CROPS*4)
#define SC_CNT    0        // u32 (memset 64 B covers it)
#define SC_CAND   64       // u64[LIST_CAP]

typedef float f32x4 __attribute__((ext_vector_type(4)));

__device__ __forceinline__ uint32_t fkey(float f) {
    uint32_t u = __float_as_uint(f);
    return (u & 0x80000000u) ? ~u : (u | 0x80000000u);
}
__device__ __forceinline__ float unfkey(uint32_t k) {
    uint32_t u = (k & 0x80000000u) ? (k & 0x7fffffffu) : ~k;
    return __uint_as_float(u);
}

// ---------------- K1: score / argmax / mask -> packed candidate list ----------------
// 8 threads per anchor-quad (10 classes each, shfl_xor argmax reduce; tie -> smaller
// class). Masked candidates are appended to a global list with ONE wave-aggregated
// atomic per wave. Key packs everything k_detect needs:
//   key64 = (fkey(score) << 32) | ((0x1FFFF ^ anchor) << 7) | cls
// Equal scores order by smaller anchor first (larger 0x1FFFF^a), matching top_k.
__global__ void k_score(const float* __restrict__ rp,
                        unsigned long long* __restrict__ cand,
                        uint32_t* __restrict__ cnt) {
    int gid = blockIdx.x * 256 + threadIdx.x;
    int grp = gid >> 3;          // anchor-quad index
    int cp  = gid & 7;           // class partition 0..7
    bool in = (grp < N_ANCH / 4);
    int a4 = in ? grp * 4 : 0;

    float best[4] = {-3.402823466e38f, -3.402823466e38f, -3.402823466e38f, -3.402823466e38f};
    int   bc[4]   = {0, 0, 0, 0};
    #pragma unroll
    for (int k = 0; k < 10; ++k) {
        int c = cp + 8 * k;
        float4 v = *(const float4*)&rp[(size_t)(5 + c) * N_ANCH + a4];
        if (v.x > best[0]) { best[0] = v.x; bc[0] = c; }
        if (v.y > best[1]) { best[1] = v.y; bc[1] = c; }
        if (v.z > best[2]) { best[2] = v.z; bc[2] = c; }
        if (v.w > best[3]) { best[3] = v.w; bc[3] = c; }
    }
    #pragma unroll
    for (int m = 1; m < 8; m <<= 1) {
        #pragma unroll
        for (int j = 0; j < 4; ++j) {
            float ob = __shfl_xor(best[j], m);
            int   oc = __shfl_xor(bc[j], m);
            if (ob > best[j] || (ob == best[j] && oc < bc[j])) { best[j] = ob; bc[j] = oc; }
        }
    }

    const unsigned long long AM =
        (1ULL << 1) | (1ULL << 2) | (1ULL << 3) | (1ULL << 4) | (1ULL << 6) |
        (1ULL << 8) | (1ULL << 17) | (1ULL << 18) | (1ULL << 44);
    unsigned long long pk[4];
    int cnt_loc = 0;
    bool lead = (cp == 0) && in;
    #pragma unroll
    for (int k = 0; k < 4; ++k) {
        int cls = bc[k] + 1;  // 1..80
        bool mk = lead && (best[k] > 0.1f) && (cls < 64) && ((AM >> cls) & 1ULL);
        uint32_t low = ((0x1FFFFu ^ (uint32_t)(a4 + k)) << 7) | (uint32_t)cls;
        pk[k] = mk ? (((unsigned long long)fkey(best[k]) << 32) | low) : 0ull;
        cnt_loc += mk ? 1 : 0;
    }

    // wave-wide exclusive prefix + single atomic
    int inc = cnt_loc;
    #pragma unroll
    for (int d = 1; d < 64; d <<= 1) {
        int vv = __shfl_up(inc, d);
        if ((threadIdx.x & 63) >= d) inc += vv;
    }
    int total = __shfl(inc, 63);
    uint32_t base = 0u;
    if (((threadIdx.x & 63) == 63) && total > 0) base = atomicAdd(cnt, (uint32_t)total);
    base = (uint32_t)__shfl((int)base, 63);
    uint32_t pos = base + (uint32_t)(inc - cnt_loc);
    #pragma unroll
    for (int k = 0; k < 4; ++k) {
        if (pk[k]) {
            if (pos < LIST_CAP) cand[pos] = pk[k];
            ++pos;
        }
    }
}

// ---------------- K2: all-LDS detect: hist -> threshold -> compact -> rank -> NMS ----
__global__ void __launch_bounds__(1024) k_detect(const float* __restrict__ rp,
                                                 const unsigned long long* __restrict__ cand,
                                                 const uint32_t* __restrict__ cnt_p,
                                                 float* __restrict__ out) {
    __shared__ uint32_t lhist[16384];                        // 64 KB: top-14-bit key bins
    __shared__ uint32_t ssum[1024];
    __shared__ uint32_t swave[16];
    __shared__ int      sh_thr;
    __shared__ uint32_t s_cnt;
    __shared__ unsigned long long sb[CAND_CAP];              // 32 KB compacted keys
    __shared__ unsigned long long top[MAX_DETS];
    __shared__ float sbx[MAX_DETS][4];
    __shared__ float sscore[MAX_DETS];
    __shared__ int   scls[MAX_DETS];
    __shared__ __align__(8) uint32_t sup[MAX_DETS][10];
    __shared__ __align__(8) uint32_t kw[10];
    __shared__ __align__(8) uint32_t rnz[10];
    int t = threadIdx.x;
    int nl = min((int)(*cnt_p), LIST_CAP);

    // ---- Phase A: LDS histogram of list keys (bin = key >> 50, 14 bits) ----
    #pragma unroll
    for (int i = 0; i < 16; ++i) lhist[t + i * 1024] = 0u;
    if (t == 0) s_cnt = 0u;
    __syncthreads();
    for (int i = t; i < nl; i += 1024)
        atomicAdd(&lhist[(uint32_t)(cand[i] >> 50)], 1u);
    __syncthreads();

    // hierarchical top-down threshold search (acc from highest bin until >= 300)
    const uint4* h4 = (const uint4*)(&lhist[t * 16]);
    uint4 v0 = h4[0], v1 = h4[1], v2 = h4[2], v3 = h4[3];
    uint32_t s = v0.x + v0.y + v0.z + v0.w + v1.x + v1.y + v1.z + v1.w +
                 v2.x + v2.y + v2.z + v2.w + v3.x + v3.y + v3.z + v3.w;
    ssum[t] = s;
    uint32_t ws = s;
    #pragma unroll
    for (int m = 32; m; m >>= 1) ws += __shfl_xor(ws, m);
    if ((t & 63) == 0) swave[t >> 6] = ws;
    __syncthreads();
    if (t == 0) {
        uint32_t acc = 0; int wsel = -1;
        for (int w = 15; w >= 0; --w) {
            uint32_t v = swave[w];
            if (acc + v >= (uint32_t)MAX_DETS) { wsel = w; break; }
            acc += v;
        }
        int thr = 0;
        if (wsel >= 0) {
            int tsel = -1;
            for (int tg = wsel * 64 + 63; tg >= wsel * 64; --tg) {
                uint32_t v = ssum[tg];
                if (acc + v >= (uint32_t)MAX_DETS) { tsel = tg; break; }
                acc += v;
            }
            for (int b = tsel * 16 + 15; b >= tsel * 16; --b) {
                acc += lhist[b];
                if (acc >= (uint32_t)MAX_DETS) { thr = b; break; }
            }
        }
        sh_thr = thr;
    }
    __syncthreads();

    // ---- Phase B: compact above-threshold keys into LDS ----
    uint32_t thr = (uint32_t)sh_thr;
    for (int i = t; i < nl; i += 1024) {
        unsigned long long key = cand[i];
        if ((uint32_t)(key >> 50) >= thr) {
            uint32_t pos = atomicAdd(&s_cnt, 1u);
            if (pos < CAND_CAP) sb[pos] = key;
        }
    }
    __syncthreads();
    int n = min((int)s_cnt, CAND_CAP);

    // ---- Phase C: exact rank selection + gather + NMS + outputs ----
    if (t < MAX_DETS) top[t] = 0ull;
    for (int i = t; i < MAX_DETS * 10; i += 1024) ((uint32_t*)sup)[i] = 0u;
    if (t < 10) { kw[t] = 0u; rnz[t] = 0u; }
    __syncthreads();

    for (int i = t; i < n; i += 1024) {
        unsigned long long key = sb[i];
        int rank = 0;
        for (int j = 0; j < n; ++j) rank += (sb[j] > key) ? 1 : 0;
        if (rank < MAX_DETS) top[rank] = key;
    }
    __syncthreads();

    if (t < MAX_DETS) {
        unsigned long long key = top[t];
        bool valid = (key != 0ull);
        float score = 0.f; int cls = 0;
        float b0 = 0.f, b1 = 0.f, b2 = 0.f, b3 = 0.f;
        if (valid) {
            uint32_t low = (uint32_t)key;
            uint32_t a = 0x1FFFFu ^ ((low >> 7) & 0x1FFFFu);
            cls = (int)(low & 0x7Fu);
            score = unfkey((uint32_t)(key >> 32));
            float cx = rp[a], cy = rp[N_ANCH + a];
            float w = rp[2 * N_ANCH + a], h = rp[3 * N_ANCH + a];
            b0 = cx - w * 0.5f; b1 = cy - h * 0.5f;
            b2 = cx + w * 0.5f; b3 = cy + h * 0.5f;
            atomicOr(&kw[t >> 5], 1u << (t & 31));
        }
        sbx[t][0] = b0; sbx[t][1] = b1; sbx[t][2] = b2; sbx[t][3] = b3;
        sscore[t] = score; scls[t] = cls;
    }
    __syncthreads();

    for (int p = t; p < MAX_DETS * MAX_DETS; p += 1024) {
        int i = p / MAX_DETS, j = p % MAX_DETS;
        if (j > i) {
            float ax1 = sbx[i][0], ay1 = sbx[i][1], ax2 = sbx[i][2], ay2 = sbx[i][3];
            float bx1 = sbx[j][0], by1 = sbx[j][1], bx2 = sbx[j][2], by2 = sbx[j][3];
            float areaA = (ax2 - ax1) * (ay2 - ay1);
            float areaB = (bx2 - bx1) * (by2 - by1);
            float ltx = fmaxf(ax1, bx1), lty = fmaxf(ay1, by1);
            float rbx = fminf(ax2, bx2), rby = fminf(ay2, by2);
            float iw = fmaxf(rbx - ltx, 0.f), ih = fmaxf(rby - lty, 0.f);
            float inter = iw * ih;
            float uni = areaA + areaB - inter;
            float iou = inter / fmaxf(uni, 1e-9f);
            if (iou > 0.45f) {
                atomicOr(&sup[i][j >> 5], 1u << (j & 31));
                atomicOr(&rnz[i >> 5], 1u << (i & 31));
            }
        }
    }
    __syncthreads();

    if (t == 0) {
        unsigned long long kwr[5], rnzr[5];
        const unsigned long long* kq = (const unsigned long long*)kw;
        const unsigned long long* rq = (const unsigned long long*)rnz;
        #pragma unroll
        for (int w = 0; w < 5; ++w) { kwr[w] = kq[w]; rnzr[w] = rq[w]; }
        #pragma unroll
        for (int sblk = 0; sblk < 5; ++sblk) {
            int lim = (sblk == 4) ? (MAX_DETS - 4 * 64) : 64;
            for (int i2 = 0; i2 < lim; ++i2) {
                if (((kwr[sblk] >> i2) & 1ull) && ((rnzr[sblk] >> i2) & 1ull)) {
                    int i = sblk * 64 + i2;
                    const unsigned long long* row = (const unsigned long long*)&sup[i][0];
                    kwr[0] &= ~row[0]; kwr[1] &= ~row[1]; kwr[2] &= ~row[2];
                    kwr[3] &= ~row[3]; kwr[4] &= ~row[4];
                }
            }
        }
        unsigned long long* kqo = (unsigned long long*)kw;
        #pragma unroll
        for (int w = 0; w < 5; ++w) kqo[w] = kwr[w];
    }
    __syncthreads();

    if (t < MAX_DETS) {
        bool kp = (kw[t >> 5] >> (t & 31)) & 1u;
        out[OFF_BOXES + t * 4 + 0] = kp ? sbx[t][0] : 0.f;
        out[OFF_BOXES + t * 4 + 1] = kp ? sbx[t][1] : 0.f;
        out[OFF_BOXES + t * 4 + 2] = kp ? sbx[t][2] : 0.f;
        out[OFF_BOXES + t * 4 + 3] = kp ? sbx[t][3] : 0.f;
        out[OFF_SCORES + t]  = kp ? sscore[t] : 0.f;
        out[OFF_CLASSES + t] = kp ? (float)scls[t] : 0.f;
        out[OFF_KEEP + t]    = kp ? 1.f : 0.f;
    }
}

// ---------------- K3: crops, 16 px/thread, row-aligned blocks, LDS-staged ROI ------
// Block = (bx in [0,14), nc in [0,903)): 16 output rows, 224 active threads
// (14 threads/row x 16 px). One y-interp per thread; per-px work is x-lerp only.
#define RPB    16
#define TROWS  22
#define TPITCH 272   // floats; stride % 32 banks = 16 -> cross-row 2-way max (free)

__device__ __forceinline__ float bilerp_g(const float* __restrict__ ch, float xc, float yc) {
    int x0 = (int)floorf(xc), y0 = (int)floorf(yc);
    int x1 = min(x0 + 1, IMG_HW - 1), y1 = min(y0 + 1, IMG_HW - 1);
    float lx = xc - (float)x0, ly = yc - (float)y0;
    float v00 = ch[y0 * IMG_HW + x0], v01 = ch[y0 * IMG_HW + x1];
    float v10 = ch[y1 * IMG_HW + x0], v11 = ch[y1 * IMG_HW + x1];
    return (v00 * (1.f - lx) + v01 * lx) * (1.f - ly) +
           (v10 * (1.f - lx) + v11 * lx) * ly;
}

__global__ void k_crops(const float* __restrict__ img, float* __restrict__ out) {
    __shared__ float tile[TROWS * TPITCH];
    int bx = blockIdx.x;             // 0..13
    int nc = blockIdx.y;             // 0..902
    int n = nc / 3, c = nc - n * 3;
    int t = threadIdx.x;
    int rl = t / 14;                 // 0..18 (active rows 0..15)
    int xs14 = t - rl * 14;
    bool act = (t < 224);
    int oy = bx * RPB + rl;
    int ox0 = xs14 * 16;
    const float meanv[3] = {0.485f, 0.456f, 0.406f};
    const float stdv[3]  = {0.229f, 0.224f, 0.225f};
    float mean = meanv[c], rstd = 1.0f / stdv[c];
    const float* ch = img + (size_t)c * (IMG_HW * IMG_HW);
    f32x4 v[4];

    if (n == 0) {
        if (act) {
            float sy = ((float)oy + 0.5f) * (1280.0f / 224.0f) - 0.5f;
            #pragma unroll
            for (int k = 0; k < 16; ++k) {
                float sx = ((float)(ox0 + k) + 0.5f) * (1280.0f / 224.0f) - 0.5f;
                v[k >> 2][k & 3] = (bilerp_g(ch, sx, sy) - mean) * rstd;
            }
        }
    } else {
        float kp = out[OFF_KEEP + (n - 1)];     // block-uniform
        if (kp == 0.f) {
            float z = (0.f - mean) * rstd;      // reference zeroes crop BEFORE normalization
            #pragma unroll
            for (int k4 = 0; k4 < 4; ++k4) v[k4] = (f32x4){z, z, z, z};
        } else {
            float4 bxv = *(const float4*)&out[OFF_BOXES + (n - 1) * 4];
            float x1b = bxv.x, y1b = bxv.y, x2b = bxv.z, y2b = bxv.w;
            float bw = x2b - x1b, bh = y2b - y1b;
            // staged region bounds (same sample formulas; monotone in oy/ox)
            float ys0 = y1b - 0.5f + (((float)(bx * RPB) + 0.5f) / 224.0f) * bh;
            float ys1 = y1b - 0.5f + (((float)(bx * RPB + RPB - 1) + 0.5f) / 224.0f) * bh;
            int iy_min = (int)floorf(fminf(fmaxf(ys0, 0.f), 1279.f));
            int iy_max = min((int)floorf(fminf(fmaxf(ys1, 0.f), 1279.f)) + 1, IMG_HW - 1);
            float xs0 = x1b - 0.5f + (0.5f / 224.0f) * bw;
            float xs1 = x1b - 0.5f + (223.5f / 224.0f) * bw;
            int ix_min = (int)floorf(fminf(fmaxf(xs0, 0.f), 1279.f));
            int ix_max = min((int)floorf(fminf(fmaxf(xs1, 0.f), 1279.f)) + 1, IMG_HW - 1);
            int ix_al = ix_min & ~3;
            int rows = iy_max - iy_min + 1;              // <= 20
            int w4   = (ix_max - ix_al + 4) >> 2;        // <= 67
            int total = rows * w4;
            float winv = 1.0f / (float)w4;
            for (int i = t; i < total; i += 256) {
                int r  = (int)((float)i * winv);
                int cc = i - r * w4;
                if (cc < 0)        { r--; cc += w4; }
                else if (cc >= w4) { r++; cc -= w4; }
                int gy = iy_min + r;
                int px = ix_al + cc * 4;
                const float* src = ch + (size_t)gy * IMG_HW + px;
                float4 val;
                if ((px + 3 < IMG_HW) || (gy < IMG_HW - 1) || (c < 2)) {
                    val = *(const float4*)src;     // in-bounds junk past x=1279 never read
                } else {
                    val.x = src[0];
                    val.y = src[min(1, IMG_HW - 1 - px)];
                    val.z = src[min(2, IMG_HW - 1 - px)];
                    val.w = src[min(3, IMG_HW - 1 - px)];
                }
                *(float4*)&tile[r * TPITCH + cc * 4] = val;
            }
            __syncthreads();
            if (act) {
                float gy = ((float)oy + 0.5f) / 224.0f;
                float ys = y1b - 0.5f + gy * bh;
                bool vy = (ys >= -1.0f) && (ys <= 1280.0f);
                float ycl = fminf(fmaxf(ys, 0.f), 1279.f);
                int y0 = (int)floorf(ycl);
                int y1i = min(y0 + 1, IMG_HW - 1);
                float ly = ycl - (float)y0;
                int ry0 = (y0 - iy_min) * TPITCH - ix_al;
                int ry1 = (y1i - iy_min) * TPITCH - ix_al;
                #pragma unroll
                for (int k = 0; k < 16; ++k) {
                    float gx = ((float)(ox0 + k) + 0.5f) / 224.0f;
                    float xs = x1b - 0.5f + gx * bw;
                    bool vx = (xs >= -1.0f) && (xs <= 1280.0f);
                    float xcl = fminf(fmaxf(xs, 0.f), 1279.f);
                    int x0 = (int)floorf(xcl);
                    int x1i = min(x0 + 1, IMG_HW - 1);
                    float lx = xcl - (float)x0;
                    float v00 = tile[ry0 + x0], v01 = tile[ry0 + x1i];
                    float v10 = tile[ry1 + x0], v11 = tile[ry1 + x1i];
                    float val = (v00 * (1.f - lx) + v01 * lx) * (1.f - ly) +
                                (v10 * (1.f - lx) + v11 * lx) * ly;
                    if (!(vx && vy)) val = 0.f;
                    v[k >> 2][k & 3] = (val - mean) * rstd;
                }
            }
        }
    }
    if (act) {
        float* dst = out + OFF_CROPS + (size_t)nc * (OUTSZ * OUTSZ) + (size_t)oy * OUTSZ + ox0;
        #pragma unroll
        for (int k4 = 0; k4 < 4; ++k4)
            __builtin_nontemporal_store(v[k4], (f32x4*)(dst + k4 * 4));
    }
}

extern "C" void kernel_launch(void* const* d_in, const int* in_sizes, int n_in,
                              void* d_out, int out_size, void* d_ws, size_t ws_size,
                              hipStream_t stream) {
    (void)in_sizes; (void)n_in; (void)out_size; (void)d_ws; (void)ws_size;
    const float* rp  = (const float*)d_in[0];
    const float* img = (const float*)d_in[1];
    float* out = (float*)d_out;
    char* sbase = (char*)d_out + (size_t)OFF_CROPS * sizeof(float);
    uint32_t* cnt = (uint32_t*)(sbase + SC_CNT);
    unsigned long long* cand = (unsigned long long*)(sbase + SC_CAND);

    hipMemsetAsync(sbase, 0, 64, stream);   // zero candidate counter
    k_score<<<(N_ANCH / 4 * 8 + 255) / 256, 256, 0, stream>>>(rp, cand, cnt);
    k_detect<<<1, 1024, 0, stream>>>(rp, cand, cnt, out);
    dim3 grid(14, 903);
    k_crops<<<grid, 256, 0, stream>>>(img, out);
}

// Round 4
// 344.042 us; speedup vs baseline: 1.1383x; 1.1383x over previous
//
#include <hip/hip_runtime.h>
#include <stdint.h>

#define N_ANCH   100800
#define NUM_CLS  80
#define IMG_HW   1280
#define MAX_DETS 300
#define OUTSZ    224
#define CAND_CAP 4096      // compacted (above-threshold) candidates in k_detect
#define LIST_CAP 16384     // raw masked candidates appended by k_score (~11k typical)

// d_out layout (float elements):
// [0,1200) boxes | [1200,1500) scores | [1500,1800) classes |
// [1800, 1800+45308928) crops | [45310728, 45311028) keep
#define OFF_BOXES   0
#define OFF_SCORES  1200
#define OFF_CLASSES 1500
#define OFF_CROPS   1800
#define CROPS_ELEMS (301 * 3 * 224 * 224)
#define OFF_KEEP    (OFF_CROPS + CROPS_ELEMS)

// scratch byte offsets inside crop region (base = (char*)d_out + OFF_CROPS*4)
#define SC_CNT    0        // u32 (memset 64 B covers it)
#define SC_CAND   64       // u64[LIST_CAP]

typedef float f32x4 __attribute__((ext_vector_type(4)));

__device__ __forceinline__ uint32_t fkey(float f) {
    uint32_t u = __float_as_uint(f);
    return (u & 0x80000000u) ? ~u : (u | 0x80000000u);
}
__device__ __forceinline__ float unfkey(uint32_t k) {
    uint32_t u = (k & 0x80000000u) ? (k & 0x7fffffffu) : ~k;
    return __uint_as_float(u);
}

// ---------------- K1: score / argmax / mask -> packed candidate list ----------------
// 8 threads per anchor-quad (10 classes each, shfl_xor argmax reduce; tie -> smaller
// class). Masked candidates appended with ONE wave-aggregated atomic per wave.
//   key64 = (fkey(score) << 32) | ((0x1FFFF ^ anchor) << 7) | cls
// Equal scores order by smaller anchor first (larger 0x1FFFF^a), matching top_k.
__global__ void k_score(const float* __restrict__ rp,
                        unsigned long long* __restrict__ cand,
                        uint32_t* __restrict__ cnt) {
    int gid = blockIdx.x * 256 + threadIdx.x;
    int grp = gid >> 3;          // anchor-quad index
    int cp  = gid & 7;           // class partition 0..7
    bool in = (grp < N_ANCH / 4);
    int a4 = in ? grp * 4 : 0;

    float best[4] = {-3.402823466e38f, -3.402823466e38f, -3.402823466e38f, -3.402823466e38f};
    int   bc[4]   = {0, 0, 0, 0};
    #pragma unroll
    for (int k = 0; k < 10; ++k) {
        int c = cp + 8 * k;
        float4 v = *(const float4*)&rp[(size_t)(5 + c) * N_ANCH + a4];
        if (v.x > best[0]) { best[0] = v.x; bc[0] = c; }
        if (v.y > best[1]) { best[1] = v.y; bc[1] = c; }
        if (v.z > best[2]) { best[2] = v.z; bc[2] = c; }
        if (v.w > best[3]) { best[3] = v.w; bc[3] = c; }
    }
    #pragma unroll
    for (int m = 1; m < 8; m <<= 1) {
        #pragma unroll
        for (int j = 0; j < 4; ++j) {
            float ob = __shfl_xor(best[j], m);
            int   oc = __shfl_xor(bc[j], m);
            if (ob > best[j] || (ob == best[j] && oc < bc[j])) { best[j] = ob; bc[j] = oc; }
        }
    }

    const unsigned long long AM =
        (1ULL << 1) | (1ULL << 2) | (1ULL << 3) | (1ULL << 4) | (1ULL << 6) |
        (1ULL << 8) | (1ULL << 17) | (1ULL << 18) | (1ULL << 44);
    unsigned long long pk[4];
    int cnt_loc = 0;
    bool lead = (cp == 0) && in;
    #pragma unroll
    for (int k = 0; k < 4; ++k) {
        int cls = bc[k] + 1;  // 1..80
        bool mk = lead && (best[k] > 0.1f) && (cls < 64) && ((AM >> cls) & 1ULL);
        uint32_t low = ((0x1FFFFu ^ (uint32_t)(a4 + k)) << 7) | (uint32_t)cls;
        pk[k] = mk ? (((unsigned long long)fkey(best[k]) << 32) | low) : 0ull;
        cnt_loc += mk ? 1 : 0;
    }

    // wave-wide exclusive prefix + single atomic
    int inc = cnt_loc;
    #pragma unroll
    for (int d = 1; d < 64; d <<= 1) {
        int vv = __shfl_up(inc, d);
        if ((threadIdx.x & 63) >= d) inc += vv;
    }
    int total = __shfl(inc, 63);
    uint32_t base = 0u;
    if (((threadIdx.x & 63) == 63) && total > 0) base = atomicAdd(cnt, (uint32_t)total);
    base = (uint32_t)__shfl((int)base, 63);
    uint32_t pos = base + (uint32_t)(inc - cnt_loc);
    #pragma unroll
    for (int k = 0; k < 4; ++k) {
        if (pk[k]) {
            if (pos < LIST_CAP) cand[pos] = pk[k];
            ++pos;
        }
    }
}

// ---------------- K2: all-LDS detect: hist -> threshold -> compact -> rank -> NMS ----
__global__ void __launch_bounds__(1024) k_detect(const float* __restrict__ rp,
                                                 const unsigned long long* __restrict__ cand,
                                                 const uint32_t* __restrict__ cnt_p,
                                                 float* __restrict__ out) {
    __shared__ uint32_t lhist[16384];                        // 64 KB: top-14-bit key bins
    __shared__ uint32_t ssum[1024];
    __shared__ uint32_t swave[16];
    __shared__ int      sh_thr;
    __shared__ uint32_t s_cnt;
    __shared__ unsigned long long sb[CAND_CAP];              // 32 KB compacted keys
    __shared__ unsigned long long top[MAX_DETS];
    __shared__ float sbx[MAX_DETS][4];
    __shared__ float sscore[MAX_DETS];
    __shared__ int   scls[MAX_DETS];
    __shared__ __align__(8) uint32_t sup[MAX_DETS][10];
    __shared__ __align__(8) uint32_t kw[10];
    __shared__ __align__(8) uint32_t rnz[10];
    int t = threadIdx.x;
    int nl = min((int)(*cnt_p), LIST_CAP);

    // ---- Phase A: LDS histogram of list keys (bin = key >> 50, 14 bits) ----
    #pragma unroll
    for (int i = 0; i < 16; ++i) lhist[t + i * 1024] = 0u;
    if (t == 0) s_cnt = 0u;
    __syncthreads();
    for (int i = t; i < nl; i += 1024)
        atomicAdd(&lhist[(uint32_t)(cand[i] >> 50)], 1u);
    __syncthreads();

    const uint4* h4 = (const uint4*)(&lhist[t * 16]);
    uint4 v0 = h4[0], v1 = h4[1], v2 = h4[2], v3 = h4[3];
    uint32_t s = v0.x + v0.y + v0.z + v0.w + v1.x + v1.y + v1.z + v1.w +
                 v2.x + v2.y + v2.z + v2.w + v3.x + v3.y + v3.z + v3.w;
    ssum[t] = s;
    uint32_t ws = s;
    #pragma unroll
    for (int m = 32; m; m >>= 1) ws += __shfl_xor(ws, m);
    if ((t & 63) == 0) swave[t >> 6] = ws;
    __syncthreads();
    if (t == 0) {
        uint32_t acc = 0; int wsel = -1;
        for (int w = 15; w >= 0; --w) {
            uint32_t v = swave[w];
            if (acc + v >= (uint32_t)MAX_DETS) { wsel = w; break; }
            acc += v;
        }
        int thr = 0;
        if (wsel >= 0) {
            int tsel = -1;
            for (int tg = wsel * 64 + 63; tg >= wsel * 64; --tg) {
                uint32_t v = ssum[tg];
                if (acc + v >= (uint32_t)MAX_DETS) { tsel = tg; break; }
                acc += v;
            }
            for (int b = tsel * 16 + 15; b >= tsel * 16; --b) {
                acc += lhist[b];
                if (acc >= (uint32_t)MAX_DETS) { thr = b; break; }
            }
        }
        sh_thr = thr;
    }
    __syncthreads();

    // ---- Phase B: compact above-threshold keys into LDS ----
    uint32_t thr = (uint32_t)sh_thr;
    for (int i = t; i < nl; i += 1024) {
        unsigned long long key = cand[i];
        if ((uint32_t)(key >> 50) >= thr) {
            uint32_t pos = atomicAdd(&s_cnt, 1u);
            if (pos < CAND_CAP) sb[pos] = key;
        }
    }
    __syncthreads();
    int n = min((int)s_cnt, CAND_CAP);

    // ---- Phase C: exact rank selection + gather + NMS + outputs ----
    if (t < MAX_DETS) top[t] = 0ull;
    for (int i = t; i < MAX_DETS * 10; i += 1024) ((uint32_t*)sup)[i] = 0u;
    if (t < 10) { kw[t] = 0u; rnz[t] = 0u; }
    __syncthreads();

    for (int i = t; i < n; i += 1024) {
        unsigned long long key = sb[i];
        int rank = 0;
        for (int j = 0; j < n; ++j) rank += (sb[j] > key) ? 1 : 0;
        if (rank < MAX_DETS) top[rank] = key;
    }
    __syncthreads();

    if (t < MAX_DETS) {
        unsigned long long key = top[t];
        bool valid = (key != 0ull);
        float score = 0.f; int cls = 0;
        float b0 = 0.f, b1 = 0.f, b2 = 0.f, b3 = 0.f;
        if (valid) {
            uint32_t low = (uint32_t)key;
            uint32_t a = 0x1FFFFu ^ ((low >> 7) & 0x1FFFFu);
            cls = (int)(low & 0x7Fu);
            score = unfkey((uint32_t)(key >> 32));
            float cx = rp[a], cy = rp[N_ANCH + a];
            float w = rp[2 * N_ANCH + a], h = rp[3 * N_ANCH + a];
            b0 = cx - w * 0.5f; b1 = cy - h * 0.5f;
            b2 = cx + w * 0.5f; b3 = cy + h * 0.5f;
            atomicOr(&kw[t >> 5], 1u << (t & 31));
        }
        sbx[t][0] = b0; sbx[t][1] = b1; sbx[t][2] = b2; sbx[t][3] = b3;
        sscore[t] = score; scls[t] = cls;
    }
    __syncthreads();

    for (int p = t; p < MAX_DETS * MAX_DETS; p += 1024) {
        int i = p / MAX_DETS, j = p % MAX_DETS;
        if (j > i) {
            float ax1 = sbx[i][0], ay1 = sbx[i][1], ax2 = sbx[i][2], ay2 = sbx[i][3];
            float bx1 = sbx[j][0], by1 = sbx[j][1], bx2 = sbx[j][2], by2 = sbx[j][3];
            float areaA = (ax2 - ax1) * (ay2 - ay1);
            float areaB = (bx2 - bx1) * (by2 - by1);
            float ltx = fmaxf(ax1, bx1), lty = fmaxf(ay1, by1);
            float rbx = fminf(ax2, bx2), rby = fminf(ay2, by2);
            float iw = fmaxf(rbx - ltx, 0.f), ih = fmaxf(rby - lty, 0.f);
            float inter = iw * ih;
            float uni = areaA + areaB - inter;
            float iou = inter / fmaxf(uni, 1e-9f);
            if (iou > 0.45f) {
                atomicOr(&sup[i][j >> 5], 1u << (j & 31));
                atomicOr(&rnz[i >> 5], 1u << (i & 31));
            }
        }
    }
    __syncthreads();

    if (t == 0) {
        unsigned long long kwr[5], rnzr[5];
        const unsigned long long* kq = (const unsigned long long*)kw;
        const unsigned long long* rq = (const unsigned long long*)rnz;
        #pragma unroll
        for (int w = 0; w < 5; ++w) { kwr[w] = kq[w]; rnzr[w] = rq[w]; }
        #pragma unroll
        for (int sblk = 0; sblk < 5; ++sblk) {
            int lim = (sblk == 4) ? (MAX_DETS - 4 * 64) : 64;
            for (int i2 = 0; i2 < lim; ++i2) {
                if (((kwr[sblk] >> i2) & 1ull) && ((rnzr[sblk] >> i2) & 1ull)) {
                    int i = sblk * 64 + i2;
                    const unsigned long long* row = (const unsigned long long*)&sup[i][0];
                    kwr[0] &= ~row[0]; kwr[1] &= ~row[1]; kwr[2] &= ~row[2];
                    kwr[3] &= ~row[3]; kwr[4] &= ~row[4];
                }
            }
        }
        unsigned long long* kqo = (unsigned long long*)kw;
        #pragma unroll
        for (int w = 0; w < 5; ++w) kqo[w] = kwr[w];
    }
    __syncthreads();

    if (t < MAX_DETS) {
        bool kp = (kw[t >> 5] >> (t & 31)) & 1u;
        out[OFF_BOXES + t * 4 + 0] = kp ? sbx[t][0] : 0.f;
        out[OFF_BOXES + t * 4 + 1] = kp ? sbx[t][1] : 0.f;
        out[OFF_BOXES + t * 4 + 2] = kp ? sbx[t][2] : 0.f;
        out[OFF_BOXES + t * 4 + 3] = kp ? sbx[t][3] : 0.f;
        out[OFF_SCORES + t]  = kp ? sscore[t] : 0.f;
        out[OFF_CLASSES + t] = kp ? (float)scls[t] : 0.f;
        out[OFF_KEEP + t]    = kp ? 1.f : 0.f;
    }
}

// ---------------- K3: crops, 4 px/thread in-row (coalesced 1KB/wave NT stores), ----
// LDS-staged ROI (8.7 KB -> high occupancy), block-uniform interior fast path.
#define TROWS  8
#define TPITCH 272   // floats; stride % 32 banks = 16 -> cross-row 2-way max (free)

__device__ __forceinline__ float bilerp_g(const float* __restrict__ ch, float xc, float yc) {
    int x0 = (int)floorf(xc), y0 = (int)floorf(yc);
    int x1 = min(x0 + 1, IMG_HW - 1), y1 = min(y0 + 1, IMG_HW - 1);
    float lx = xc - (float)x0, ly = yc - (float)y0;
    float v00 = ch[y0 * IMG_HW + x0], v01 = ch[y0 * IMG_HW + x1];
    float v10 = ch[y1 * IMG_HW + x0], v11 = ch[y1 * IMG_HW + x1];
    return (v00 * (1.f - lx) + v01 * lx) * (1.f - ly) +
           (v10 * (1.f - lx) + v11 * lx) * ly;
}

__global__ void k_crops(const float* __restrict__ img, float* __restrict__ out) {
    __shared__ float tile[TROWS * TPITCH];
    int bx = blockIdx.x;             // 0..48
    int nc = blockIdx.y;             // 0..902
    int n = nc / 3, c = nc - n * 3;
    int t = threadIdx.x;
    int q = bx * 256 + t;            // 0..12543 (exact: 49*256 = 56*224)
    int oy = q / 56;
    int ox0 = (q - oy * 56) * 4;
    const float meanv[3] = {0.485f, 0.456f, 0.406f};
    const float stdv[3]  = {0.229f, 0.224f, 0.225f};
    float mean = meanv[c], rstd = 1.0f / stdv[c];
    const float* ch = img + (size_t)c * (IMG_HW * IMG_HW);
    f32x4 v;

    if (n == 0) {
        // jax.image.resize linear, antialias=False: all samples interior
        float sy = ((float)oy + 0.5f) * (1280.0f / 224.0f) - 0.5f;
        #pragma unroll
        for (int k = 0; k < 4; ++k) {
            float sx = ((float)(ox0 + k) + 0.5f) * (1280.0f / 224.0f) - 0.5f;
            v[k] = (bilerp_g(ch, sx, sy) - mean) * rstd;
        }
    } else {
        float kp = out[OFF_KEEP + (n - 1)];     // block-uniform
        if (kp == 0.f) {
            float z = (0.f - mean) * rstd;      // reference zeroes crop BEFORE normalization
            v = (f32x4){z, z, z, z};
        } else {
            float4 bxv = *(const float4*)&out[OFF_BOXES + (n - 1) * 4];
            float x1b = bxv.x, y1b = bxv.y, x2b = bxv.z, y2b = bxv.w;
            float bw = x2b - x1b, bh = y2b - y1b;
            float x1bm = x1b - 0.5f, y1bm = y1b - 0.5f;
            // block-uniform sample extremes (same formulas as the per-px gather)
            int oy_s = (bx * 256) / 56;
            int oy_e = (bx * 256 + 255) / 56;
            float ys0 = y1bm + (((float)oy_s + 0.5f) / 224.0f) * bh;
            float ys1 = y1bm + (((float)oy_e + 0.5f) / 224.0f) * bh;
            float xs0 = x1bm + (0.5f / 224.0f) * bw;
            float xs1 = x1bm + (223.5f / 224.0f) * bw;
            int iy_min = (int)floorf(fminf(fmaxf(ys0, 0.f), 1279.f));
            int iy_max = min((int)floorf(fminf(fmaxf(ys1, 0.f), 1279.f)) + 1, IMG_HW - 1);
            int ix_min = (int)floorf(fminf(fmaxf(xs0, 0.f), 1279.f));
            int ix_max = min((int)floorf(fminf(fmaxf(xs1, 0.f), 1279.f)) + 1, IMG_HW - 1);
            int ix_al = ix_min & ~3;
            int rows = iy_max - iy_min + 1;              // <= 8
            int w4   = (ix_max - ix_al + 4) >> 2;        // <= 68
            int total = rows * w4;
            float winv = 1.0f / (float)w4;
            for (int i = t; i < total; i += 256) {
                int r  = (int)((float)i * winv);
                int cc = i - r * w4;
                if (cc < 0)        { r--; cc += w4; }
                else if (cc >= w4) { r++; cc -= w4; }
                int gy = iy_min + r;
                int px = ix_al + cc * 4;
                const float* src = ch + (size_t)gy * IMG_HW + px;
                float4 val;
                if ((px + 3 < IMG_HW) || (gy < IMG_HW - 1) || (c < 2)) {
                    val = *(const float4*)src;     // in-bounds junk past x=1279 never read
                } else {
                    val.x = src[0];
                    val.y = src[min(1, IMG_HW - 1 - px)];
                    val.z = src[min(2, IMG_HW - 1 - px)];
                    val.w = src[min(3, IMG_HW - 1 - px)];
                }
                *(float4*)&tile[r * TPITCH + cc * 4] = val;
            }
            __syncthreads();

            bool interior = (xs0 >= 0.0f) && (xs1 < 1279.0f) &&
                            (ys0 >= 0.0f) && (ys1 < 1279.0f);   // block-uniform
            float gy = ((float)oy + 0.5f) / 224.0f;
            float ys = y1bm + gy * bh;
            if (interior) {
                // no clamps, no validity selects; x1i=x0+1, y1i=y0+1 always staged
                float y0f = floorf(ys);
                float ly = ys - y0f;
                int y0 = (int)y0f;
                int ry0 = (y0 - iy_min) * TPITCH - ix_al;
                int ry1 = ry0 + TPITCH;
                #pragma unroll
                for (int k = 0; k < 4; ++k) {
                    float gx = ((float)(ox0 + k) + 0.5f) / 224.0f;
                    float xs = x1bm + gx * bw;
                    float x0f = floorf(xs);
                    float lx = xs - x0f;
                    int x0 = (int)x0f;
                    int a0 = ry0 + x0, a1 = ry1 + x0;
                    float t00 = tile[a0], t01 = tile[a0 + 1];   // ds_read2 pair
                    float t10 = tile[a1], t11 = tile[a1 + 1];
                    float top = __builtin_fmaf(lx, t01 - t00, t00);
                    float bot = __builtin_fmaf(lx, t11 - t10, t10);
                    float val = __builtin_fmaf(ly, bot - top, top);
                    v[k] = (val - mean) * rstd;
                }
            } else {
                bool vy = (ys >= -1.0f) && (ys <= 1280.0f);
                float ycl = fminf(fmaxf(ys, 0.f), 1279.f);
                int y0 = (int)floorf(ycl);
                int y1i = min(y0 + 1, IMG_HW - 1);
                float ly = ycl - (float)y0;
                int ry0 = (y0 - iy_min) * TPITCH - ix_al;
                int ry1 = (y1i - iy_min) * TPITCH - ix_al;
                #pragma unroll
                for (int k = 0; k < 4; ++k) {
                    float gx = ((float)(ox0 + k) + 0.5f) / 224.0f;
                    float xs = x1bm + gx * bw;
                    bool vx = (xs >= -1.0f) && (xs <= 1280.0f);
                    float xcl = fminf(fmaxf(xs, 0.f), 1279.f);
                    int x0 = (int)floorf(xcl);
                    int x1i = min(x0 + 1, IMG_HW - 1);
                    float lx = xcl - (float)x0;
                    float v00 = tile[ry0 + x0], v01 = tile[ry0 + x1i];
                    float v10 = tile[ry1 + x0], v11 = tile[ry1 + x1i];
                    float val = (v00 * (1.f - lx) + v01 * lx) * (1.f - ly) +
                                (v10 * (1.f - lx) + v11 * lx) * ly;
                    if (!(vx && vy)) val = 0.f;
                    v[k] = (val - mean) * rstd;
                }
            }
        }
    }
    f32x4* dst = (f32x4*)(out + OFF_CROPS + (size_t)nc * (OUTSZ * OUTSZ) + oy * OUTSZ + ox0);
    __builtin_nontemporal_store(v, dst);
}

extern "C" void kernel_launch(void* const* d_in, const int* in_sizes, int n_in,
                              void* d_out, int out_size, void* d_ws, size_t ws_size,
                              hipStream_t stream) {
    (void)in_sizes; (void)n_in; (void)out_size; (void)d_ws; (void)ws_size;
    const float* rp  = (const float*)d_in[0];
    const float* img = (const float*)d_in[1];
    float* out = (float*)d_out;
    char* sbase = (char*)d_out + (size_t)OFF_CROPS * sizeof(float);
    uint32_t* cnt = (uint32_t*)(sbase + SC_CNT);
    unsigned long long* cand = (unsigned long long*)(sbase + SC_CAND);

    hipMemsetAsync(sbase, 0, 64, stream);   // zero candidate counter
    k_score<<<(N_ANCH / 4 * 8 + 255) / 256, 256, 0, stream>>>(rp, cand, cnt);
    k_detect<<<1, 1024, 0, stream>>>(rp, cand, cnt, out);
    dim3 grid(49, 903);
    k_crops<<<grid, 256, 0, stream>>>(img, out);
}

// Round 5
// 326.950 us; speedup vs baseline: 1.1978x; 1.0523x over previous
//
#include <hip/hip_runtime.h>
#include <stdint.h>

#define N_ANCH   100800
#define NUM_CLS  80
#define IMG_HW   1280
#define MAX_DETS 300
#define OUTSZ    224
#define CAND_CAP 4096      // compacted (above-threshold) candidates in k_detect
#define LIST_CAP 16384     // raw masked candidates appended by k_score (~11k typical)

// d_out layout (float elements):
// [0,1200) boxes | [1200,1500) scores | [1500,1800) classes |
// [1800, 1800+45308928) crops | [45310728, 45311028) keep
#define OFF_BOXES   0
#define OFF_SCORES  1200
#define OFF_CLASSES 1500
#define OFF_CROPS   1800
#define CROPS_ELEMS (301 * 3 * 224 * 224)
#define OFF_KEEP    (OFF_CROPS + CROPS_ELEMS)

// scratch byte offsets inside crop region (base = (char*)d_out + OFF_CROPS*4)
#define SC_CNT    0        // u32 (memset 64 B covers it)
#define SC_CAND   64       // u64[LIST_CAP]

typedef float f32x4 __attribute__((ext_vector_type(4)));

__device__ __forceinline__ uint32_t fkey(float f) {
    uint32_t u = __float_as_uint(f);
    return (u & 0x80000000u) ? ~u : (u | 0x80000000u);
}
__device__ __forceinline__ float unfkey(uint32_t k) {
    uint32_t u = (k & 0x80000000u) ? (k & 0x7fffffffu) : ~k;
    return __uint_as_float(u);
}

// ---------------- K1: score / argmax / mask -> packed candidate list ----------------
// 8 threads per anchor-quad (10 classes each, shfl_xor argmax reduce; tie -> smaller
// class). Masked candidates appended with ONE wave-aggregated atomic per wave.
//   key64 = (fkey(score) << 32) | ((0x1FFFF ^ anchor) << 7) | cls
// Equal scores order by smaller anchor first (larger 0x1FFFF^a), matching top_k.
__global__ void k_score(const float* __restrict__ rp,
                        unsigned long long* __restrict__ cand,
                        uint32_t* __restrict__ cnt) {
    int gid = blockIdx.x * 256 + threadIdx.x;
    int grp = gid >> 3;          // anchor-quad index
    int cp  = gid & 7;           // class partition 0..7
    bool in = (grp < N_ANCH / 4);
    int a4 = in ? grp * 4 : 0;

    float best[4] = {-3.402823466e38f, -3.402823466e38f, -3.402823466e38f, -3.402823466e38f};
    int   bc[4]   = {0, 0, 0, 0};
    #pragma unroll
    for (int k = 0; k < 10; ++k) {
        int c = cp + 8 * k;
        float4 v = *(const float4*)&rp[(size_t)(5 + c) * N_ANCH + a4];
        if (v.x > best[0]) { best[0] = v.x; bc[0] = c; }
        if (v.y > best[1]) { best[1] = v.y; bc[1] = c; }
        if (v.z > best[2]) { best[2] = v.z; bc[2] = c; }
        if (v.w > best[3]) { best[3] = v.w; bc[3] = c; }
    }
    #pragma unroll
    for (int m = 1; m < 8; m <<= 1) {
        #pragma unroll
        for (int j = 0; j < 4; ++j) {
            float ob = __shfl_xor(best[j], m);
            int   oc = __shfl_xor(bc[j], m);
            if (ob > best[j] || (ob == best[j] && oc < bc[j])) { best[j] = ob; bc[j] = oc; }
        }
    }

    const unsigned long long AM =
        (1ULL << 1) | (1ULL << 2) | (1ULL << 3) | (1ULL << 4) | (1ULL << 6) |
        (1ULL << 8) | (1ULL << 17) | (1ULL << 18) | (1ULL << 44);
    unsigned long long pk[4];
    int cnt_loc = 0;
    bool lead = (cp == 0) && in;
    #pragma unroll
    for (int k = 0; k < 4; ++k) {
        int cls = bc[k] + 1;  // 1..80
        bool mk = lead && (best[k] > 0.1f) && (cls < 64) && ((AM >> cls) & 1ULL);
        uint32_t low = ((0x1FFFFu ^ (uint32_t)(a4 + k)) << 7) | (uint32_t)cls;
        pk[k] = mk ? (((unsigned long long)fkey(best[k]) << 32) | low) : 0ull;
        cnt_loc += mk ? 1 : 0;
    }

    // wave-wide exclusive prefix + single atomic
    int inc = cnt_loc;
    #pragma unroll
    for (int d = 1; d < 64; d <<= 1) {
        int vv = __shfl_up(inc, d);
        if ((threadIdx.x & 63) >= d) inc += vv;
    }
    int total = __shfl(inc, 63);
    uint32_t base = 0u;
    if (((threadIdx.x & 63) == 63) && total > 0) base = atomicAdd(cnt, (uint32_t)total);
    base = (uint32_t)__shfl((int)base, 63);
    uint32_t pos = base + (uint32_t)(inc - cnt_loc);
    #pragma unroll
    for (int k = 0; k < 4; ++k) {
        if (pk[k]) {
            if (pos < LIST_CAP) cand[pos] = pk[k];
            ++pos;
        }
    }
}

// ---------------- K2: all-LDS detect: hist -> threshold -> compact -> rank -> NMS ----
__global__ void __launch_bounds__(1024) k_detect(const float* __restrict__ rp,
                                                 const unsigned long long* __restrict__ cand,
                                                 const uint32_t* __restrict__ cnt_p,
                                                 float* __restrict__ out) {
    __shared__ uint32_t lhist[16384];                        // 64 KB: top-14-bit key bins
    __shared__ uint32_t ssum[1024];
    __shared__ uint32_t swave[16];
    __shared__ int      sh_thr;
    __shared__ uint32_t s_cnt;
    __shared__ unsigned long long sb[CAND_CAP];              // 32 KB compacted keys
    __shared__ unsigned long long top[MAX_DETS];
    __shared__ float sbx[MAX_DETS][4];
    __shared__ float sscore[MAX_DETS];
    __shared__ int   scls[MAX_DETS];
    __shared__ __align__(8) uint32_t sup[MAX_DETS][10];
    __shared__ __align__(8) uint32_t kw[10];
    __shared__ __align__(8) uint32_t rnz[10];
    int t = threadIdx.x;
    int nl = min((int)(*cnt_p), LIST_CAP);

    // ---- Phase A: LDS histogram of list keys (bin = key >> 50, 14 bits) ----
    #pragma unroll
    for (int i = 0; i < 16; ++i) lhist[t + i * 1024] = 0u;
    if (t == 0) s_cnt = 0u;
    __syncthreads();
    for (int i = t; i < nl; i += 1024)
        atomicAdd(&lhist[(uint32_t)(cand[i] >> 50)], 1u);
    __syncthreads();

    const uint4* h4 = (const uint4*)(&lhist[t * 16]);
    uint4 v0 = h4[0], v1 = h4[1], v2 = h4[2], v3 = h4[3];
    uint32_t s = v0.x + v0.y + v0.z + v0.w + v1.x + v1.y + v1.z + v1.w +
                 v2.x + v2.y + v2.z + v2.w + v3.x + v3.y + v3.z + v3.w;
    ssum[t] = s;
    uint32_t ws = s;
    #pragma unroll
    for (int m = 32; m; m >>= 1) ws += __shfl_xor(ws, m);
    if ((t & 63) == 0) swave[t >> 6] = ws;
    __syncthreads();
    if (t == 0) {
        uint32_t acc = 0; int wsel = -1;
        for (int w = 15; w >= 0; --w) {
            uint32_t v = swave[w];
            if (acc + v >= (uint32_t)MAX_DETS) { wsel = w; break; }
            acc += v;
        }
        int thr = 0;
        if (wsel >= 0) {
            int tsel = -1;
            for (int tg = wsel * 64 + 63; tg >= wsel * 64; --tg) {
                uint32_t v = ssum[tg];
                if (acc + v >= (uint32_t)MAX_DETS) { tsel = tg; break; }
                acc += v;
            }
            for (int b = tsel * 16 + 15; b >= tsel * 16; --b) {
                acc += lhist[b];
                if (acc >= (uint32_t)MAX_DETS) { thr = b; break; }
            }
        }
        sh_thr = thr;
    }
    __syncthreads();

    // ---- Phase B: compact above-threshold keys into LDS ----
    uint32_t thr = (uint32_t)sh_thr;
    for (int i = t; i < nl; i += 1024) {
        unsigned long long key = cand[i];
        if ((uint32_t)(key >> 50) >= thr) {
            uint32_t pos = atomicAdd(&s_cnt, 1u);
            if (pos < CAND_CAP) sb[pos] = key;
        }
    }
    __syncthreads();
    int n = min((int)s_cnt, CAND_CAP);

    // ---- Phase C: exact rank selection + gather + NMS + outputs ----
    if (t < MAX_DETS) top[t] = 0ull;
    for (int i = t; i < MAX_DETS * 10; i += 1024) ((uint32_t*)sup)[i] = 0u;
    if (t < 10) { kw[t] = 0u; rnz[t] = 0u; }
    __syncthreads();

    for (int i = t; i < n; i += 1024) {
        unsigned long long key = sb[i];
        int rank = 0;
        for (int j = 0; j < n; ++j) rank += (sb[j] > key) ? 1 : 0;
        if (rank < MAX_DETS) top[rank] = key;
    }
    __syncthreads();

    if (t < MAX_DETS) {
        unsigned long long key = top[t];
        bool valid = (key != 0ull);
        float score = 0.f; int cls = 0;
        float b0 = 0.f, b1 = 0.f, b2 = 0.f, b3 = 0.f;
        if (valid) {
            uint32_t low = (uint32_t)key;
            uint32_t a = 0x1FFFFu ^ ((low >> 7) & 0x1FFFFu);
            cls = (int)(low & 0x7Fu);
            score = unfkey((uint32_t)(key >> 32));
            float cx = rp[a], cy = rp[N_ANCH + a];
            float w = rp[2 * N_ANCH + a], h = rp[3 * N_ANCH + a];
            b0 = cx - w * 0.5f; b1 = cy - h * 0.5f;
            b2 = cx + w * 0.5f; b3 = cy + h * 0.5f;
            atomicOr(&kw[t >> 5], 1u << (t & 31));
        }
        sbx[t][0] = b0; sbx[t][1] = b1; sbx[t][2] = b2; sbx[t][3] = b3;
        sscore[t] = score; scls[t] = cls;
    }
    __syncthreads();

    for (int p = t; p < MAX_DETS * MAX_DETS; p += 1024) {
        int i = p / MAX_DETS, j = p % MAX_DETS;
        if (j > i) {
            float ax1 = sbx[i][0], ay1 = sbx[i][1], ax2 = sbx[i][2], ay2 = sbx[i][3];
            float bx1 = sbx[j][0], by1 = sbx[j][1], bx2 = sbx[j][2], by2 = sbx[j][3];
            float areaA = (ax2 - ax1) * (ay2 - ay1);
            float areaB = (bx2 - bx1) * (by2 - by1);
            float ltx = fmaxf(ax1, bx1), lty = fmaxf(ay1, by1);
            float rbx = fminf(ax2, bx2), rby = fminf(ay2, by2);
            float iw = fmaxf(rbx - ltx, 0.f), ih = fmaxf(rby - lty, 0.f);
            float inter = iw * ih;
            float uni = areaA + areaB - inter;
            float iou = inter / fmaxf(uni, 1e-9f);
            if (iou > 0.45f) {
                atomicOr(&sup[i][j >> 5], 1u << (j & 31));
                atomicOr(&rnz[i >> 5], 1u << (i & 31));
            }
        }
    }
    __syncthreads();

    if (t == 0) {
        unsigned long long kwr[5], rnzr[5];
        const unsigned long long* kq = (const unsigned long long*)kw;
        const unsigned long long* rq = (const unsigned long long*)rnz;
        #pragma unroll
        for (int w = 0; w < 5; ++w) { kwr[w] = kq[w]; rnzr[w] = rq[w]; }
        #pragma unroll
        for (int sblk = 0; sblk < 5; ++sblk) {
            int lim = (sblk == 4) ? (MAX_DETS - 4 * 64) : 64;
            for (int i2 = 0; i2 < lim; ++i2) {
                if (((kwr[sblk] >> i2) & 1ull) && ((rnzr[sblk] >> i2) & 1ull)) {
                    int i = sblk * 64 + i2;
                    const unsigned long long* row = (const unsigned long long*)&sup[i][0];
                    kwr[0] &= ~row[0]; kwr[1] &= ~row[1]; kwr[2] &= ~row[2];
                    kwr[3] &= ~row[3]; kwr[4] &= ~row[4];
                }
            }
        }
        unsigned long long* kqo = (unsigned long long*)kw;
        #pragma unroll
        for (int w = 0; w < 5; ++w) kqo[w] = kwr[w];
    }
    __syncthreads();

    if (t < MAX_DETS) {
        bool kp = (kw[t >> 5] >> (t & 31)) & 1u;
        out[OFF_BOXES + t * 4 + 0] = kp ? sbx[t][0] : 0.f;
        out[OFF_BOXES + t * 4 + 1] = kp ? sbx[t][1] : 0.f;
        out[OFF_BOXES + t * 4 + 2] = kp ? sbx[t][2] : 0.f;
        out[OFF_BOXES + t * 4 + 3] = kp ? sbx[t][3] : 0.f;
        out[OFF_SCORES + t]  = kp ? sscore[t] : 0.f;
        out[OFF_CLASSES + t] = kp ? (float)scls[t] : 0.f;
        out[OFF_KEEP + t]    = kp ? 1.f : 0.f;
    }
}

// ---------------- K3: crops, channel-merged: one block = 3 channels of one ---------
// (crop n, row-band bx). Sampling coords (ys/y0/ly + per-k x0/x1/lx/valid) are
// channel-independent -> computed ONCE into registers, reused for c=0,1,2.
// Per channel: stage plane rows into the same 8.7 KB LDS tile (barrier-restage),
// 4 LDS taps + 3 fma lerp + 1 fma normalize per px, coalesced 1KB/wave NT store.
#define TROWS  8
#define TPITCH 272   // floats; stride % 32 banks = 16 -> cross-row 2-way max (free)

__global__ void k_crops(const float* __restrict__ img, float* __restrict__ out) {
    __shared__ float tile[TROWS * TPITCH];
    int bx = blockIdx.x;             // 0..48
    int n  = blockIdx.y;             // 0..300
    int t = threadIdx.x;
    int q = bx * 256 + t;            // 0..12543 (exact: 49*256 = 56*224)
    int oy = q / 56;
    int ox0 = (q - oy * 56) * 4;
    // normalize: val/std - mean/std  ==  fma(val, scl, bia); keep==0 value == bia
    const float scl[3] = {1.0f / 0.229f, 1.0f / 0.224f, 1.0f / 0.225f};
    const float bia[3] = {-0.485f / 0.229f, -0.456f / 0.224f, -0.406f / 0.225f};
    size_t obase = (size_t)OFF_CROPS + (size_t)(n * 3) * (OUTSZ * OUTSZ)
                 + (size_t)oy * OUTSZ + ox0;

    if (n == 0) {
        // jax.image.resize linear, antialias=False: all samples interior
        // (min 2.36, max 1276.65 -> +1 tap <= 1277); coords shared across channels.
        float sy = ((float)oy + 0.5f) * (1280.0f / 224.0f) - 0.5f;
        int y0 = (int)floorf(sy);
        float ly = sy - (float)y0;
        int x0a[4]; float lxa[4];
        #pragma unroll
        for (int k = 0; k < 4; ++k) {
            float sx = ((float)(ox0 + k) + 0.5f) * (1280.0f / 224.0f) - 0.5f;
            x0a[k] = (int)floorf(sx);
            lxa[k] = sx - floorf(sx);
        }
        #pragma unroll
        for (int c = 0; c < 3; ++c) {
            const float* r0 = img + (size_t)c * (IMG_HW * IMG_HW) + (size_t)y0 * IMG_HW;
            const float* r1 = r0 + IMG_HW;
            f32x4 v;
            #pragma unroll
            for (int k = 0; k < 4; ++k) {
                float t00 = r0[x0a[k]], t01 = r0[x0a[k] + 1];
                float t10 = r1[x0a[k]], t11 = r1[x0a[k] + 1];
                float top = __builtin_fmaf(lxa[k], t01 - t00, t00);
                float bot = __builtin_fmaf(lxa[k], t11 - t10, t10);
                float val = __builtin_fmaf(ly, bot - top, top);
                v[k] = __builtin_fmaf(val, scl[c], bia[c]);
            }
            __builtin_nontemporal_store(v, (f32x4*)(out + obase + (size_t)c * (OUTSZ * OUTSZ)));
        }
        return;
    }

    float kp = out[OFF_KEEP + (n - 1)];     // block-uniform
    if (kp == 0.f) {
        #pragma unroll
        for (int c = 0; c < 3; ++c) {
            f32x4 v = (f32x4){bia[c], bia[c], bia[c], bia[c]};
            __builtin_nontemporal_store(v, (f32x4*)(out + obase + (size_t)c * (OUTSZ * OUTSZ)));
        }
        return;
    }

    float4 bxv = *(const float4*)&out[OFF_BOXES + (n - 1) * 4];
    float x1b = bxv.x, y1b = bxv.y, x2b = bxv.z, y2b = bxv.w;
    float bw = x2b - x1b, bh = y2b - y1b;
    float x1bm = x1b - 0.5f, y1bm = y1b - 0.5f;
    // block-uniform staged-region bounds (same formulas as the per-px sampling)
    int oy_s = (bx * 256) / 56;
    int oy_e = (bx * 256 + 255) / 56;
    float ys0 = y1bm + (((float)oy_s + 0.5f) / 224.0f) * bh;
    float ys1 = y1bm + (((float)oy_e + 0.5f) / 224.0f) * bh;
    float xs0 = x1bm + (0.5f / 224.0f) * bw;
    float xs1 = x1bm + (223.5f / 224.0f) * bw;
    int iy_min = (int)floorf(fminf(fmaxf(ys0, 0.f), 1279.f));
    int iy_max = min((int)floorf(fminf(fmaxf(ys1, 0.f), 1279.f)) + 1, IMG_HW - 1);
    int ix_min = (int)floorf(fminf(fmaxf(xs0, 0.f), 1279.f));
    int ix_max = min((int)floorf(fminf(fmaxf(xs1, 0.f), 1279.f)) + 1, IMG_HW - 1);
    int ix_al = ix_min & ~3;
    int rows = iy_max - iy_min + 1;              // <= 8
    int w4   = (ix_max - ix_al + 4) >> 2;        // <= 68
    int total = rows * w4;
    float winv = 1.0f / (float)w4;

    // ---- per-thread sampling coords, computed once (channel-independent) ----
    float gy = ((float)oy + 0.5f) / 224.0f;
    float ys = y1bm + gy * bh;
    bool vy = (ys >= -1.0f) && (ys <= 1280.0f);
    float ycl = fminf(fmaxf(ys, 0.f), 1279.f);
    int y0 = (int)floorf(ycl);
    int y1i = min(y0 + 1, IMG_HW - 1);
    float ly = ycl - (float)y0;
    int rb0 = (y0 - iy_min) * TPITCH - ix_al;
    int rb1 = (y1i - iy_min) * TPITCH - ix_al;
    int a0a[4], a1a[4];     // tile offsets for x0 taps (row0/row1)
    int d1a[4];             // +1 or 0 (x1 clamp) added to both
    float lxa[4]; bool oka[4];
    #pragma unroll
    for (int k = 0; k < 4; ++k) {
        float gx = ((float)(ox0 + k) + 0.5f) / 224.0f;
        float xs = x1bm + gx * bw;
        oka[k] = vy && (xs >= -1.0f) && (xs <= 1280.0f);
        float xcl = fminf(fmaxf(xs, 0.f), 1279.f);
        int x0 = (int)floorf(xcl);
        int x1i = min(x0 + 1, IMG_HW - 1);
        lxa[k] = xcl - (float)x0;
        a0a[k] = rb0 + x0;
        a1a[k] = rb1 + x0;
        d1a[k] = x1i - x0;
    }

    // ---- per-channel: stage plane -> lerp from LDS -> NT store ----
    for (int c = 0; c < 3; ++c) {
        if (c) __syncthreads();                  // prior channel's reads done
        const float* ch = img + (size_t)c * (IMG_HW * IMG_HW);
        for (int i = t; i < total; i += 256) {
            int r  = (int)((float)i * winv);
            int cc = i - r * w4;
            if (cc < 0)        { r--; cc += w4; }
            else if (cc >= w4) { r++; cc -= w4; }
            int gyr = iy_min + r;
            int px = ix_al + cc * 4;
            const float* src = ch + (size_t)gyr * IMG_HW + px;
            float4 val;
            if ((px + 3 < IMG_HW) || (gyr < IMG_HW - 1) || (c < 2)) {
                val = *(const float4*)src;       // in-bounds junk past x=1279 never read
            } else {
                val.x = src[0];
                val.y = src[min(1, IMG_HW - 1 - px)];
                val.z = src[min(2, IMG_HW - 1 - px)];
                val.w = src[min(3, IMG_HW - 1 - px)];
            }
            *(float4*)&tile[r * TPITCH + cc * 4] = val;
        }
        __syncthreads();
        f32x4 v;
        #pragma unroll
        for (int k = 0; k < 4; ++k) {
            float t00 = tile[a0a[k]], t01 = tile[a0a[k] + d1a[k]];
            float t10 = tile[a1a[k]], t11 = tile[a1a[k] + d1a[k]];
            float top = __builtin_fmaf(lxa[k], t01 - t00, t00);
            float bot = __builtin_fmaf(lxa[k], t11 - t10, t10);
            float val = __builtin_fmaf(ly, bot - top, top);
            if (!oka[k]) val = 0.f;
            v[k] = __builtin_fmaf(val, scl[c], bia[c]);
        }
        __builtin_nontemporal_store(v, (f32x4*)(out + obase + (size_t)c * (OUTSZ * OUTSZ)));
    }
}

extern "C" void kernel_launch(void* const* d_in, const int* in_sizes, int n_in,
                              void* d_out, int out_size, void* d_ws, size_t ws_size,
                              hipStream_t stream) {
    (void)in_sizes; (void)n_in; (void)out_size; (void)d_ws; (void)ws_size;
    const float* rp  = (const float*)d_in[0];
    const float* img = (const float*)d_in[1];
    float* out = (float*)d_out;
    char* sbase = (char*)d_out + (size_t)OFF_CROPS * sizeof(float);
    uint32_t* cnt = (uint32_t*)(sbase + SC_CNT);
    unsigned long long* cand = (unsigned long long*)(sbase + SC_CAND);

    hipMemsetAsync(sbase, 0, 64, stream);   // zero candidate counter
    k_score<<<(N_ANCH / 4 * 8 + 255) / 256, 256, 0, stream>>>(rp, cand, cnt);
    k_detect<<<1, 1024, 0, stream>>>(rp, cand, cnt, out);
    dim3 grid(49, 301);
    k_crops<<<grid, 256, 0, stream>>>(img, out);
}

// Round 6
// 324.108 us; speedup vs baseline: 1.2083x; 1.0088x over previous
//
#include <hip/hip_runtime.h>
#include <stdint.h>

#define N_ANCH   100800
#define NUM_CLS  80
#define IMG_HW   1280
#define MAX_DETS 300
#define OUTSZ    224
#define CAND_CAP 4096      // compacted (above-threshold) candidates in k_detect
#define LIST_CAP 16384     // raw masked candidates appended by k_score (~11k typical)

// d_out layout (float elements):
// [0,1200) boxes | [1200,1500) scores | [1500,1800) classes |
// [1800, 1800+45308928) crops | [45310728, 45311028) keep
#define OFF_BOXES   0
#define OFF_SCORES  1200
#define OFF_CLASSES 1500
#define OFF_CROPS   1800
#define CROPS_ELEMS (301 * 3 * 224 * 224)
#define OFF_KEEP    (OFF_CROPS + CROPS_ELEMS)

// scratch byte offsets inside crop region (base = (char*)d_out + OFF_CROPS*4)
#define SC_CNT    0        // u32 (memset 64 B covers it)
#define SC_CAND   64       // u64[LIST_CAP]

typedef float f32x4 __attribute__((ext_vector_type(4)));

__device__ __forceinline__ uint32_t fkey(float f) {
    uint32_t u = __float_as_uint(f);
    return (u & 0x80000000u) ? ~u : (u | 0x80000000u);
}
__device__ __forceinline__ float unfkey(uint32_t k) {
    uint32_t u = (k & 0x80000000u) ? (k & 0x7fffffffu) : ~k;
    return __uint_as_float(u);
}

// ---------------- K1: score / argmax / mask -> packed candidate list ----------------
// 8 threads per anchor-quad (10 classes each, shfl_xor argmax reduce; tie -> smaller
// class). Masked candidates appended with ONE wave-aggregated atomic per wave.
//   key64 = (fkey(score) << 32) | ((0x1FFFF ^ anchor) << 7) | cls
// Equal scores order by smaller anchor first (larger 0x1FFFF^a), matching top_k.
__global__ void k_score(const float* __restrict__ rp,
                        unsigned long long* __restrict__ cand,
                        uint32_t* __restrict__ cnt) {
    int gid = blockIdx.x * 256 + threadIdx.x;
    int grp = gid >> 3;          // anchor-quad index
    int cp  = gid & 7;           // class partition 0..7
    bool in = (grp < N_ANCH / 4);
    int a4 = in ? grp * 4 : 0;

    float best[4] = {-3.402823466e38f, -3.402823466e38f, -3.402823466e38f, -3.402823466e38f};
    int   bc[4]   = {0, 0, 0, 0};
    #pragma unroll
    for (int k = 0; k < 10; ++k) {
        int c = cp + 8 * k;
        float4 v = *(const float4*)&rp[(size_t)(5 + c) * N_ANCH + a4];
        if (v.x > best[0]) { best[0] = v.x; bc[0] = c; }
        if (v.y > best[1]) { best[1] = v.y; bc[1] = c; }
        if (v.z > best[2]) { best[2] = v.z; bc[2] = c; }
        if (v.w > best[3]) { best[3] = v.w; bc[3] = c; }
    }
    #pragma unroll
    for (int m = 1; m < 8; m <<= 1) {
        #pragma unroll
        for (int j = 0; j < 4; ++j) {
            float ob = __shfl_xor(best[j], m);
            int   oc = __shfl_xor(bc[j], m);
            if (ob > best[j] || (ob == best[j] && oc < bc[j])) { best[j] = ob; bc[j] = oc; }
        }
    }

    const unsigned long long AM =
        (1ULL << 1) | (1ULL << 2) | (1ULL << 3) | (1ULL << 4) | (1ULL << 6) |
        (1ULL << 8) | (1ULL << 17) | (1ULL << 18) | (1ULL << 44);
    unsigned long long pk[4];
    int cnt_loc = 0;
    bool lead = (cp == 0) && in;
    #pragma unroll
    for (int k = 0; k < 4; ++k) {
        int cls = bc[k] + 1;  // 1..80
        bool mk = lead && (best[k] > 0.1f) && (cls < 64) && ((AM >> cls) & 1ULL);
        uint32_t low = ((0x1FFFFu ^ (uint32_t)(a4 + k)) << 7) | (uint32_t)cls;
        pk[k] = mk ? (((unsigned long long)fkey(best[k]) << 32) | low) : 0ull;
        cnt_loc += mk ? 1 : 0;
    }

    // wave-wide exclusive prefix + single atomic
    int inc = cnt_loc;
    #pragma unroll
    for (int d = 1; d < 64; d <<= 1) {
        int vv = __shfl_up(inc, d);
        if ((threadIdx.x & 63) >= d) inc += vv;
    }
    int total = __shfl(inc, 63);
    uint32_t base = 0u;
    if (((threadIdx.x & 63) == 63) && total > 0) base = atomicAdd(cnt, (uint32_t)total);
    base = (uint32_t)__shfl((int)base, 63);
    uint32_t pos = base + (uint32_t)(inc - cnt_loc);
    #pragma unroll
    for (int k = 0; k < 4; ++k) {
        if (pk[k]) {
            if (pos < LIST_CAP) cand[pos] = pk[k];
            ++pos;
        }
    }
}

// ---------------- K2: all-LDS detect: hist -> threshold -> compact -> rank -> NMS ----
__global__ void __launch_bounds__(1024) k_detect(const float* __restrict__ rp,
                                                 const unsigned long long* __restrict__ cand,
                                                 const uint32_t* __restrict__ cnt_p,
                                                 float* __restrict__ out) {
    __shared__ uint32_t lhist[16384];                        // 64 KB: top-14-bit key bins
    __shared__ uint32_t ssum[1024];
    __shared__ uint32_t swave[16];
    __shared__ int      sh_thr;
    __shared__ uint32_t s_cnt;
    __shared__ unsigned long long sb[CAND_CAP];              // 32 KB compacted keys
    __shared__ unsigned long long top[MAX_DETS];
    __shared__ float sbx[MAX_DETS][4];
    __shared__ float sscore[MAX_DETS];
    __shared__ int   scls[MAX_DETS];
    __shared__ __align__(8) uint32_t sup[MAX_DETS][10];
    __shared__ __align__(8) uint32_t kw[10];
    __shared__ __align__(8) uint32_t rnz[10];
    int t = threadIdx.x;
    int nl = min((int)(*cnt_p), LIST_CAP);

    // ---- Phase A: LDS histogram of list keys (bin = key >> 50, 14 bits) ----
    #pragma unroll
    for (int i = 0; i < 16; ++i) lhist[t + i * 1024] = 0u;
    if (t == 0) s_cnt = 0u;
    __syncthreads();
    for (int i = t; i < nl; i += 1024)
        atomicAdd(&lhist[(uint32_t)(cand[i] >> 50)], 1u);
    __syncthreads();

    const uint4* h4 = (const uint4*)(&lhist[t * 16]);
    uint4 v0 = h4[0], v1 = h4[1], v2 = h4[2], v3 = h4[3];
    uint32_t s = v0.x + v0.y + v0.z + v0.w + v1.x + v1.y + v1.z + v1.w +
                 v2.x + v2.y + v2.z + v2.w + v3.x + v3.y + v3.z + v3.w;
    ssum[t] = s;
    uint32_t ws = s;
    #pragma unroll
    for (int m = 32; m; m >>= 1) ws += __shfl_xor(ws, m);
    if ((t & 63) == 0) swave[t >> 6] = ws;
    __syncthreads();
    if (t == 0) {
        uint32_t acc = 0; int wsel = -1;
        for (int w = 15; w >= 0; --w) {
            uint32_t v = swave[w];
            if (acc + v >= (uint32_t)MAX_DETS) { wsel = w; break; }
            acc += v;
        }
        int thr = 0;
        if (wsel >= 0) {
            int tsel = -1;
            for (int tg = wsel * 64 + 63; tg >= wsel * 64; --tg) {
                uint32_t v = ssum[tg];
                if (acc + v >= (uint32_t)MAX_DETS) { tsel = tg; break; }
                acc += v;
            }
            for (int b = tsel * 16 + 15; b >= tsel * 16; --b) {
                acc += lhist[b];
                if (acc >= (uint32_t)MAX_DETS) { thr = b; break; }
            }
        }
        sh_thr = thr;
    }
    __syncthreads();

    // ---- Phase B: compact above-threshold keys into LDS ----
    uint32_t thr = (uint32_t)sh_thr;
    for (int i = t; i < nl; i += 1024) {
        unsigned long long key = cand[i];
        if ((uint32_t)(key >> 50) >= thr) {
            uint32_t pos = atomicAdd(&s_cnt, 1u);
            if (pos < CAND_CAP) sb[pos] = key;
        }
    }
    __syncthreads();
    int n = min((int)s_cnt, CAND_CAP);

    // ---- Phase C: exact rank selection + gather + NMS + outputs ----
    if (t < MAX_DETS) top[t] = 0ull;
    for (int i = t; i < MAX_DETS * 10; i += 1024) ((uint32_t*)sup)[i] = 0u;
    if (t < 10) { kw[t] = 0u; rnz[t] = 0u; }
    __syncthreads();

    for (int i = t; i < n; i += 1024) {
        unsigned long long key = sb[i];
        int rank = 0;
        for (int j = 0; j < n; ++j) rank += (sb[j] > key) ? 1 : 0;
        if (rank < MAX_DETS) top[rank] = key;
    }
    __syncthreads();

    if (t < MAX_DETS) {
        unsigned long long key = top[t];
        bool valid = (key != 0ull);
        float score = 0.f; int cls = 0;
        float b0 = 0.f, b1 = 0.f, b2 = 0.f, b3 = 0.f;
        if (valid) {
            uint32_t low = (uint32_t)key;
            uint32_t a = 0x1FFFFu ^ ((low >> 7) & 0x1FFFFu);
            cls = (int)(low & 0x7Fu);
            score = unfkey((uint32_t)(key >> 32));
            float cx = rp[a], cy = rp[N_ANCH + a];
            float w = rp[2 * N_ANCH + a], h = rp[3 * N_ANCH + a];
            b0 = cx - w * 0.5f; b1 = cy - h * 0.5f;
            b2 = cx + w * 0.5f; b3 = cy + h * 0.5f;
            atomicOr(&kw[t >> 5], 1u << (t & 31));
        }
        sbx[t][0] = b0; sbx[t][1] = b1; sbx[t][2] = b2; sbx[t][3] = b3;
        sscore[t] = score; scls[t] = cls;
    }
    __syncthreads();

    for (int p = t; p < MAX_DETS * MAX_DETS; p += 1024) {
        int i = p / MAX_DETS, j = p % MAX_DETS;
        if (j > i) {
            float ax1 = sbx[i][0], ay1 = sbx[i][1], ax2 = sbx[i][2], ay2 = sbx[i][3];
            float bx1 = sbx[j][0], by1 = sbx[j][1], bx2 = sbx[j][2], by2 = sbx[j][3];
            float areaA = (ax2 - ax1) * (ay2 - ay1);
            float areaB = (bx2 - bx1) * (by2 - by1);
            float ltx = fmaxf(ax1, bx1), lty = fmaxf(ay1, by1);
            float rbx = fminf(ax2, bx2), rby = fminf(ay2, by2);
            float iw = fmaxf(rbx - ltx, 0.f), ih = fmaxf(rby - lty, 0.f);
            float inter = iw * ih;
            float uni = areaA + areaB - inter;
            float iou = inter / fmaxf(uni, 1e-9f);
            if (iou > 0.45f) {
                atomicOr(&sup[i][j >> 5], 1u << (j & 31));
                atomicOr(&rnz[i >> 5], 1u << (i & 31));
            }
        }
    }
    __syncthreads();

    if (t == 0) {
        unsigned long long kwr[5], rnzr[5];
        const unsigned long long* kq = (const unsigned long long*)kw;
        const unsigned long long* rq = (const unsigned long long*)rnz;
        #pragma unroll
        for (int w = 0; w < 5; ++w) { kwr[w] = kq[w]; rnzr[w] = rq[w]; }
        #pragma unroll
        for (int sblk = 0; sblk < 5; ++sblk) {
            int lim = (sblk == 4) ? (MAX_DETS - 4 * 64) : 64;
            for (int i2 = 0; i2 < lim; ++i2) {
                if (((kwr[sblk] >> i2) & 1ull) && ((rnzr[sblk] >> i2) & 1ull)) {
                    int i = sblk * 64 + i2;
                    const unsigned long long* row = (const unsigned long long*)&sup[i][0];
                    kwr[0] &= ~row[0]; kwr[1] &= ~row[1]; kwr[2] &= ~row[2];
                    kwr[3] &= ~row[3]; kwr[4] &= ~row[4];
                }
            }
        }
        unsigned long long* kqo = (unsigned long long*)kw;
        #pragma unroll
        for (int w = 0; w < 5; ++w) kqo[w] = kwr[w];
    }
    __syncthreads();

    if (t < MAX_DETS) {
        bool kp = (kw[t >> 5] >> (t & 31)) & 1u;
        out[OFF_BOXES + t * 4 + 0] = kp ? sbx[t][0] : 0.f;
        out[OFF_BOXES + t * 4 + 1] = kp ? sbx[t][1] : 0.f;
        out[OFF_BOXES + t * 4 + 2] = kp ? sbx[t][2] : 0.f;
        out[OFF_BOXES + t * 4 + 3] = kp ? sbx[t][3] : 0.f;
        out[OFF_SCORES + t]  = kp ? sscore[t] : 0.f;
        out[OFF_CLASSES + t] = kp ? (float)scls[t] : 0.f;
        out[OFF_KEEP + t]    = kp ? 1.f : 0.f;
    }
}

// ---------------- K3: crops, channel-merged + double-buffered + paired taps --------
// One block = 3 channels of one (crop n, row-band bx). Coords computed once.
// Double-buffered LDS staging: stage channel c+1 while computing channel c
// (3 barriers/block instead of 6; loads overlap lerp+store).
// Right-edge column replicated into the tile (from global, no race) so taps are
// always tile[a], tile[a+1] with literal +1 -> compiler pairs into ds_read2_b32.
// rep => ix_al >= 1012 => D+1 <= 268 < TPITCH: replica never collides (proof:
// rep needs xs1 >= 1278, span <= 263 => ix_min >= 1015).
#define TROWS  8
#define TPITCH 272   // floats; stride % 32 banks = 16 -> cross-row 2-way max (free)
#define TSIZE  (TROWS * TPITCH)

__global__ void k_crops(const float* __restrict__ img, float* __restrict__ out) {
    __shared__ float tile[2][TSIZE + 4];
    int bx = blockIdx.x;             // 0..48
    int n  = blockIdx.y;             // 0..300
    int t = threadIdx.x;
    int q = bx * 256 + t;            // 0..12543 (exact: 49*256 = 56*224)
    int oy = q / 56;
    int ox0 = (q - oy * 56) * 4;
    // normalize: val/std - mean/std  ==  fma(val, scl, bia); keep==0 value == bia
    const float scl[3] = {1.0f / 0.229f, 1.0f / 0.224f, 1.0f / 0.225f};
    const float bia[3] = {-0.485f / 0.229f, -0.456f / 0.224f, -0.406f / 0.225f};
    size_t obase = (size_t)OFF_CROPS + (size_t)(n * 3) * (OUTSZ * OUTSZ)
                 + (size_t)oy * OUTSZ + ox0;

    if (n == 0) {
        // jax.image.resize linear, antialias=False: all samples interior
        float sy = ((float)oy + 0.5f) * (1280.0f / 224.0f) - 0.5f;
        int y0 = (int)floorf(sy);
        float ly = sy - (float)y0;
        int x0a[4]; float lxa[4];
        #pragma unroll
        for (int k = 0; k < 4; ++k) {
            float sx = ((float)(ox0 + k) + 0.5f) * (1280.0f / 224.0f) - 0.5f;
            x0a[k] = (int)floorf(sx);
            lxa[k] = sx - floorf(sx);
        }
        #pragma unroll
        for (int c = 0; c < 3; ++c) {
            const float* r0 = img + (size_t)c * (IMG_HW * IMG_HW) + (size_t)y0 * IMG_HW;
            const float* r1 = r0 + IMG_HW;
            f32x4 v;
            #pragma unroll
            for (int k = 0; k < 4; ++k) {
                float t00 = r0[x0a[k]], t01 = r0[x0a[k] + 1];
                float t10 = r1[x0a[k]], t11 = r1[x0a[k] + 1];
                float top = __builtin_fmaf(lxa[k], t01 - t00, t00);
                float bot = __builtin_fmaf(lxa[k], t11 - t10, t10);
                float val = __builtin_fmaf(ly, bot - top, top);
                v[k] = __builtin_fmaf(val, scl[c], bia[c]);
            }
            __builtin_nontemporal_store(v, (f32x4*)(out + obase + (size_t)c * (OUTSZ * OUTSZ)));
        }
        return;
    }

    float kp = out[OFF_KEEP + (n - 1)];     // block-uniform
    if (kp == 0.f) {
        #pragma unroll
        for (int c = 0; c < 3; ++c) {
            f32x4 v = (f32x4){bia[c], bia[c], bia[c], bia[c]};
            __builtin_nontemporal_store(v, (f32x4*)(out + obase + (size_t)c * (OUTSZ * OUTSZ)));
        }
        return;
    }

    float4 bxv = *(const float4*)&out[OFF_BOXES + (n - 1) * 4];
    float x1b = bxv.x, y1b = bxv.y, x2b = bxv.z, y2b = bxv.w;
    float bw = x2b - x1b, bh = y2b - y1b;
    float x1bm = x1b - 0.5f, y1bm = y1b - 0.5f;
    // block-uniform staged-region bounds (same formulas as the per-px sampling)
    int oy_s = (bx * 256) / 56;
    int oy_e = (bx * 256 + 255) / 56;
    float ys0 = y1bm + (((float)oy_s + 0.5f) / 224.0f) * bh;
    float ys1 = y1bm + (((float)oy_e + 0.5f) / 224.0f) * bh;
    float xs0 = x1bm + (0.5f / 224.0f) * bw;
    float xs1 = x1bm + (223.5f / 224.0f) * bw;
    int iy_min = (int)floorf(fminf(fmaxf(ys0, 0.f), 1279.f));
    int iy_max = min((int)floorf(fminf(fmaxf(ys1, 0.f), 1279.f)) + 1, IMG_HW - 1);
    int ix_min = (int)floorf(fminf(fmaxf(xs0, 0.f), 1279.f));
    int ix_max = min((int)floorf(fminf(fmaxf(xs1, 0.f), 1279.f)) + 1, IMG_HW - 1);
    int ix_al = ix_min & ~3;
    int rows = iy_max - iy_min + 1;              // <= 8
    int w4   = (ix_max - ix_al + 4) >> 2;        // <= 68 (w4*4 <= 272)
    int total = rows * w4;
    float winv = 1.0f / (float)w4;
    int D = (IMG_HW - 1) - ix_al;                // right-edge tile column
    bool rep = (ix_max == IMG_HW - 1);

    // ---- staging descriptors, computed once (channel-independent, static idx) ----
    int soff[3], doff[3], px3[3]; bool sval[3], safe4[3];
    #pragma unroll
    for (int s = 0; s < 3; ++s) {
        int i = t + s * 256;
        sval[s] = (i < total);
        int r  = (int)((float)i * winv);
        int cc = i - r * w4;
        if (cc < 0)        { r--; cc += w4; }
        else if (cc >= w4) { r++; cc -= w4; }
        int gyr = iy_min + r;
        int px = ix_al + cc * 4;
        soff[s]  = gyr * IMG_HW + px;
        doff[s]  = r * TPITCH + cc * 4;
        safe4[s] = (px + 3 < IMG_HW) || (gyr < IMG_HW - 1);  // only last img row+chan unsafe
        px3[s]   = IMG_HW - 1 - px;
    }

    // ---- per-thread sampling coords, computed once (channel-independent) ----
    float gy = ((float)oy + 0.5f) / 224.0f;
    float ys = y1bm + gy * bh;
    bool vy = (ys >= -1.0f) && (ys <= 1280.0f);
    float ycl = fminf(fmaxf(ys, 0.f), 1279.f);
    int y0 = (int)floorf(ycl);
    int y1i = min(y0 + 1, IMG_HW - 1);
    float ly = ycl - (float)y0;
    int rb0 = (y0 - iy_min) * TPITCH - ix_al;
    int rb1 = (y1i - iy_min) * TPITCH - ix_al;
    int a0a[4], a1a[4]; float lxa[4]; bool oka[4];
    #pragma unroll
    for (int k = 0; k < 4; ++k) {
        float gx = ((float)(ox0 + k) + 0.5f) / 224.0f;
        float xs = x1bm + gx * bw;
        oka[k] = vy && (xs >= -1.0f) && (xs <= 1280.0f);
        float xcl = fminf(fmaxf(xs, 0.f), 1279.f);
        int x0 = (int)floorf(xcl);
        lxa[k] = xcl - (float)x0;           // x0==1279 -> lx==0 -> +1 tap mult by 0
        a0a[k] = rb0 + x0;
        a1a[k] = rb1 + x0;
    }

    // ---- staging helper (writes buffer b from channel c) ----
    auto stage = [&](float* __restrict__ tb, int c) {
        const float* __restrict__ ch = img + (size_t)c * (IMG_HW * IMG_HW);
        #pragma unroll
        for (int s = 0; s < 3; ++s) {
            if (sval[s]) {
                const float* src = ch + soff[s];
                float4 val;
                if (safe4[s] || c < 2) {
                    val = *(const float4*)src;   // in-bounds junk past x=1279 never read
                } else {
                    val.x = src[0];
                    val.y = src[min(1, px3[s])];
                    val.z = src[min(2, px3[s])];
                    val.w = src[min(3, px3[s])];
                }
                *(float4*)&tb[doff[s]] = val;
            }
        }
        if (rep) {      // replicate x=1279 column so tile[a+1] is always valid
            for (int r2 = t; r2 < rows; r2 += 256)
                tb[r2 * TPITCH + D + 1] = ch[(size_t)(iy_min + r2) * IMG_HW + (IMG_HW - 1)];
        }
    };

    // ---- double-buffered channel pipeline ----
    stage(tile[0], 0);
    __syncthreads();
    #pragma unroll
    for (int c = 0; c < 3; ++c) {
        if (c < 2) stage(tile[(c + 1) & 1], c + 1);
        const float* __restrict__ tb = tile[c & 1];
        f32x4 v;
        #pragma unroll
        for (int k = 0; k < 4; ++k) {
            float t00 = tb[a0a[k]], t01 = tb[a0a[k] + 1];   // ds_read2_b32 pair
            float t10 = tb[a1a[k]], t11 = tb[a1a[k] + 1];   // ds_read2_b32 pair
            float top = __builtin_fmaf(lxa[k], t01 - t00, t00);
            float bot = __builtin_fmaf(lxa[k], t11 - t10, t10);
            float val = __builtin_fmaf(ly, bot - top, top);
            if (!oka[k]) val = 0.f;
            v[k] = __builtin_fmaf(val, scl[c], bia[c]);
        }
        __builtin_nontemporal_store(v, (f32x4*)(out + obase + (size_t)c * (OUTSZ * OUTSZ)));
        if (c < 2) __syncthreads();
    }
}

extern "C" void kernel_launch(void* const* d_in, const int* in_sizes, int n_in,
                              void* d_out, int out_size, void* d_ws, size_t ws_size,
                              hipStream_t stream) {
    (void)in_sizes; (void)n_in; (void)out_size; (void)d_ws; (void)ws_size;
    const float* rp  = (const float*)d_in[0];
    const float* img = (const float*)d_in[1];
    float* out = (float*)d_out;
    char* sbase = (char*)d_out + (size_t)OFF_CROPS * sizeof(float);
    uint32_t* cnt = (uint32_t*)(sbase + SC_CNT);
    unsigned long long* cand = (unsigned long long*)(sbase + SC_CAND);

    hipMemsetAsync(sbase, 0, 64, stream);   // zero candidate counter
    k_score<<<(N_ANCH / 4 * 8 + 255) / 256, 256, 0, stream>>>(rp, cand, cnt);
    k_detect<<<1, 1024, 0, stream>>>(rp, cand, cnt, out);
    dim3 grid(49, 301);
    k_crops<<<grid, 256, 0, stream>>>(img, out);
}